// Round 8
// baseline (186.332 us; speedup 1.0000x reference)
//
#include <hip/hip_runtime.h>
#include <math.h>

#define IMG 512
#define TW 64        // stripe width
#define RAD 5
#define HWP 68       // dwords per field-row (16B-aligned)
#define RSTR 340     // 5*HWP dwords per ring row
#define RING 32      // ring rows (power of 2, >= 26 live rows)
#define MMB 1024

struct W11 { float w[11]; };

__device__ __forceinline__ unsigned omap(float f) {
  unsigned b = __float_as_uint(f);
  return (b & 0x80000000u) ? ~b : (b | 0x80000000u);
}
__device__ __forceinline__ float ounmap(unsigned u) {
  return __uint_as_float((u & 0x80000000u) ? (u ^ 0x80000000u) : ~u);
}

// Stage 1: per-block partial min/max -> disjoint slots, no atomics.
__global__ __launch_bounds__(256) void minmax_part(const float4* __restrict__ img,
                                                   int n4, unsigned* __restrict__ part) {
  unsigned mx = 0u, mn = 0xFFFFFFFFu;
  int stride = gridDim.x * blockDim.x;
  for (int i = blockIdx.x * blockDim.x + threadIdx.x; i < n4; i += stride) {
    float4 v = img[i];
    unsigned a = omap(v.x), b = omap(v.y), c = omap(v.z), d = omap(v.w);
    mx = max(mx, max(max(a, b), max(c, d)));
    mn = min(mn, min(min(a, b), min(c, d)));
  }
  #pragma unroll
  for (int off = 32; off > 0; off >>= 1) {
    mx = max(mx, __shfl_down(mx, off));
    mn = min(mn, __shfl_down(mn, off));
  }
  __shared__ unsigned smx[4], smn[4];
  int lane = threadIdx.x & 63, wv = threadIdx.x >> 6;
  if (lane == 0) { smx[wv] = mx; smn[wv] = mn; }
  __syncthreads();
  if (threadIdx.x == 0) {
    mx = max(max(smx[0], smx[1]), max(smx[2], smx[3]));
    mn = min(min(smn[0], smn[1]), min(smn[2], smn[3]));
    part[2 * blockIdx.x]     = mx;
    part[2 * blockIdx.x + 1] = mn;
  }
}

__global__ __launch_bounds__(256) void minmax_final(const unsigned* __restrict__ part,
                                                    unsigned* __restrict__ ws) {
  unsigned mx = 0u, mn = 0xFFFFFFFFu;
  for (int i = threadIdx.x; i < MMB; i += 256) {
    mx = max(mx, part[2 * i]);
    mn = min(mn, part[2 * i + 1]);
  }
  #pragma unroll
  for (int off = 32; off > 0; off >>= 1) {
    mx = max(mx, __shfl_down(mx, off));
    mn = min(mn, __shfl_down(mn, off));
  }
  __shared__ unsigned smx[4], smn[4];
  int lane = threadIdx.x & 63, wv = threadIdx.x >> 6;
  if (lane == 0) { smx[wv] = mx; smn[wv] = mn; }
  __syncthreads();
  if (threadIdx.x == 0) {
    ws[0] = max(max(smx[0], smx[1]), max(smx[2], smx[3]));
    ws[1] = min(min(smn[0], smn[1]), min(smn[2], smn[3]));
  }
}

// One h-conv task: row gy, 4 cols starting xg; writes 5 field values x4 cols
// into ring slot. Direct global reads (L1 absorbs overlap).
__device__ __forceinline__ void h_task(const float* __restrict__ p1,
                                       const float* __restrict__ p2,
                                       float* Hs, int gy, int xbase, int xg,
                                       bool x_ok, int slot, const W11& wv) {
  float A20[20], B20[20];
  float* aa = &A20[3];    // aa[t] = input at x = xbase + xg + t
  float* bb = &B20[3];

  bool y_in = (gy >= 0) & (gy < IMG);
  if (!y_in) {
    #pragma unroll
    for (int t = 0; t < 14; ++t) { aa[t] = 0.f; bb[t] = 0.f; }
  } else if (x_ok) {
    // xbase+xg-3 = bx*64 + xg - 8: multiple of 4 -> 16B-aligned float4 loads
    const float* r1 = p1 + gy * IMG + (xbase + xg - 3);
    const float* r2 = p2 + gy * IMG + (xbase + xg - 3);
    #pragma unroll
    for (int m = 0; m < 5; ++m) *(float4*)&A20[4 * m] = *(const float4*)(r1 + 4 * m);
    #pragma unroll
    for (int m = 0; m < 5; ++m) *(float4*)&B20[4 * m] = *(const float4*)(r2 + 4 * m);
  } else {
    const float* r1 = p1 + gy * IMG;
    const float* r2 = p2 + gy * IMG;
    #pragma unroll
    for (int t = 0; t < 14; ++t) {
      int x = xbase + xg + t;
      bool ok = (x >= 0) & (x < IMG);
      aa[t] = ok ? r1[x] : 0.f;
      bb[t] = ok ? r2[x] : 0.f;
    }
  }

  float a2[14], b2[14], ab[14];
  #pragma unroll
  for (int t = 0; t < 14; ++t) {
    a2[t] = aa[t] * aa[t]; b2[t] = bb[t] * bb[t]; ab[t] = aa[t] * bb[t];
  }

  float acc[5][4];
  #pragma unroll
  for (int f = 0; f < 5; ++f)
    #pragma unroll
    for (int j = 0; j < 4; ++j) acc[f][j] = 0.f;

  #pragma unroll
  for (int k = 0; k < 11; ++k) {
    float wk = wv.w[k];
    #pragma unroll
    for (int j = 0; j < 4; ++j) {
      acc[0][j] += wk * aa[j + k];
      acc[1][j] += wk * bb[j + k];
      acc[2][j] += wk * a2[j + k];
      acc[3][j] += wk * b2[j + k];
      acc[4][j] += wk * ab[j + k];
    }
  }
  float* dst = Hs + slot * RSTR + xg;
  #pragma unroll
  for (int f = 0; f < 5; ++f)
    *(float4*)&dst[f * HWP] = make_float4(acc[f][0], acc[f][1], acc[f][2], acc[f][3]);
}

// Column-stripe persistent SSIM: each block walks a 64-wide stripe segment in
// 16-row steps, h-fields kept in a 32-row LDS ring. h-halo recompute drops
// from 1.625x to ~1.06x, global-load addressing amortizes across the stripe.
// grid = 8 x 3 x 32 = 768 blocks = exactly 3/CU (LDS 43.5KB -> 3 blocks/CU).
__global__ __launch_bounds__(256, 3) void ssim_k(const float* __restrict__ img1,
                                                 const float* __restrict__ img2,
                                                 float* __restrict__ out,
                                                 const unsigned* __restrict__ ws,
                                                 W11 wv) {
  __shared__ float Hs[RING * RSTR];   // [ring][field][HWP], 43,520 B

  const int tid = threadIdx.x;
  const int bx = blockIdx.x, by = blockIdx.y, n = blockIdx.z;
  const float* p1 = img1 + (size_t)n * IMG * IMG;
  const float* p2 = img2 + (size_t)n * IMG * IMG;

  const int ybase = by * 176;                  // 176/176/160 row segments
  const int rows  = (by < 2) ? 176 : 160;
  const int ni    = rows >> 4;                 // 11/11/10 iterations
  const int xbase = bx * TW - RAD;
  const bool x_ok = (bx > 0) & (bx < IMG / TW - 1);

  // C1/C2 from global min/max (ws written by previous dispatch)
  float L = ounmap(ws[0]) - ounmap(ws[1]);
  if (L == 0.f) L = 5.f;
  float C1 = 0.01f * L; C1 *= C1;
  float C2 = 0.03f * L; C2 *= C2;

  // ---- prologue: fill ring rows L = 0..25 (416 tasks) ----
  #pragma unroll
  for (int it = 0; it < 2; ++it) {
    int g = tid + (it << 8);
    if (g < 416) {
      int Lr = g >> 4;
      int xg = (g & 15) << 2;
      h_task(p1, p2, Hs, ybase - RAD + Lr, xbase, xg, x_ok, Lr, wv);
    }
  }
  __syncthreads();

  const int c4 = (tid & 15) << 2;   // 4 cols
  const int ro = tid >> 4;          // row-in-step 0..15

  for (int iter = 0; iter < ni; ++iter) {
    // ---- v-pass: output local row o, 4 cols; ring rows (o+k)&31 ----
    int o = (iter << 4) + ro;
    float4 acc[5];
    #pragma unroll
    for (int f = 0; f < 5; ++f) acc[f] = make_float4(0.f, 0.f, 0.f, 0.f);

    #pragma unroll
    for (int k = 0; k < 11; ++k) {
      float wk = wv.w[k];
      const float4* row = (const float4*)(Hs + ((o + k) & (RING - 1)) * RSTR + c4);
      #pragma unroll
      for (int f = 0; f < 5; ++f) {
        float4 v = row[f * (HWP / 4)];   // immediate offsets f*272B
        acc[f].x += wk * v.x; acc[f].y += wk * v.y;
        acc[f].z += wk * v.z; acc[f].w += wk * v.w;
      }
    }

    const float* m1  = (const float*)&acc[0];
    const float* m2  = (const float*)&acc[1];
    const float* e11 = (const float*)&acc[2];
    const float* e22 = (const float*)&acc[3];
    const float* e12 = (const float*)&acc[4];
    float4 res; float* rp = (float*)&res;
    #pragma unroll
    for (int j = 0; j < 4; ++j) {
      float mu1 = m1[j], mu2 = m2[j];
      float mu1s = mu1 * mu1, mu2s = mu2 * mu2, mu12 = mu1 * mu2;
      float s1 = e11[j] - mu1s, s2 = e22[j] - mu2s, s12 = e12[j] - mu12;
      float num = (2.f * mu12 + C1) * (2.f * s12 + C2);
      float den = (mu1s + mu2s + C1) * (s1 + s2 + C2);
      rp[j] = num * __builtin_amdgcn_rcpf(den);   // rel err ~1e-7 << threshold
    }
    int gy = ybase + o, gx = bx * TW + c4;
    *(float4*)&out[(size_t)n * IMG * IMG + (size_t)gy * IMG + gx] = res;

    __syncthreads();   // all v-reads done before ring slots are overwritten

    // ---- h-pass for next iter: 16 new rows L = 26+16*iter .. +15 ----
    if (iter + 1 < ni) {
      int Lr = 26 + (iter << 4) + ro;
      h_task(p1, p2, Hs, ybase - RAD + Lr, xbase, c4, x_ok, Lr & (RING - 1), wv);
    }
    __syncthreads();   // new h-rows visible to next v-pass
  }
}

extern "C" void kernel_launch(void* const* d_in, const int* in_sizes, int n_in,
                              void* d_out, int out_size, void* d_ws, size_t ws_size,
                              hipStream_t stream) {
  const float* img1 = (const float*)d_in[0];
  const float* img2 = (const float*)d_in[1];
  float* out = (float*)d_out;
  unsigned* ws = (unsigned*)d_ws;          // [0..1]: final max/min; [16..]: partials
  unsigned* part = ws + 16;
  int n = in_sizes[0];             // 32*1*512*512
  int batch = n / (IMG * IMG);     // 32

  // Gaussian window, center at ws/2 = 5.5 (asymmetric!), normalized
  W11 wv;
  double g[11], s = 0.0;
  for (int i = 0; i < 11; ++i) { double d = i - 5.5; g[i] = exp(-(d * d) / 4.5); s += g[i]; }
  for (int i = 0; i < 11; ++i) wv.w[i] = (float)(g[i] / s);

  minmax_part<<<MMB, 256, 0, stream>>>((const float4*)img1, n / 4, part);
  minmax_final<<<1, 256, 0, stream>>>(part, ws);
  dim3 grid(IMG / TW, 3, batch);   // 8 x 3 x 32 = 768 blocks = 3/CU exactly
  ssim_k<<<grid, 256, 0, stream>>>(img1, img2, out, ws, wv);
}